// Round 1
// baseline (121.030 us; speedup 1.0000x reference)
//
#include <hip/hip_runtime.h>

// LengthRegulator: B=32, T=256, D=384, MAX_LEN=2048
// out[b,f,:] = x[b, searchsorted(csum[b], f, 'right'), :] if f < mel_len[b] else 0
// mel_len[b] = csum[b, T-1]

#define BB 32
#define TT 256
#define DD 384
#define MAXLEN 2048
#define D4 (DD / 4)            // 96 float4 per frame
#define FPB 8                  // frames per block (expand)
#define TILES (MAXLEN / FPB)   // 256 tiles per batch

__global__ __launch_bounds__(256) void scan_kernel(const int* __restrict__ duration,
                                                   int* __restrict__ csum,
                                                   float* __restrict__ mel_out) {
    __shared__ int s[TT];
    const int b = blockIdx.x;
    const int t = threadIdx.x;
    s[t] = duration[b * TT + t];
    __syncthreads();
    // Hillis-Steele inclusive scan over 256 elements
    for (int off = 1; off < TT; off <<= 1) {
        int cur = s[t];
        int add = (t >= off) ? s[t - off] : 0;
        __syncthreads();
        s[t] = cur + add;
        __syncthreads();
    }
    csum[b * TT + t] = s[t];
    if (t == TT - 1) {
        // Output buffer is fp32; mel_len written as float value.
        mel_out[b] = (float)s[t];
    }
}

__global__ __launch_bounds__(256) void expand_kernel(const float* __restrict__ x,
                                                     const int* __restrict__ csum,
                                                     float* __restrict__ out) {
    __shared__ int s_csum[TT];
    __shared__ int s_idx[FPB];

    const int bid = blockIdx.x;
    const int b = bid >> 8;          // bid / TILES (TILES == 256)
    const int tile = bid & (TILES - 1);
    const int tid = threadIdx.x;

    s_csum[tid] = csum[b * TT + tid];
    __syncthreads();

    if (tid < FPB) {
        const int f = tile * FPB + tid;
        const int mel = s_csum[TT - 1];
        int idx = -1;
        if (f < mel) {
            // upper_bound: first index with csum[idx] > f  (searchsorted side='right')
            int lo = 0, hi = TT;
            while (lo < hi) {
                int mid = (lo + hi) >> 1;
                if (s_csum[mid] > f) hi = mid; else lo = mid + 1;
            }
            idx = lo;  // f < csum[TT-1] guarantees lo <= TT-1, so clip is a no-op
        }
        s_idx[tid] = idx;
    }
    __syncthreads();

    const float4* __restrict__ x4 = (const float4*)(x + (size_t)b * TT * DD);
    float4* __restrict__ o4 = (float4*)(out + ((size_t)b * MAXLEN + (size_t)tile * FPB) * DD);

    // FPB * D4 = 768 float4 per block tile; 256 threads -> 3 fully-coalesced iterations
    #pragma unroll
    for (int i = 0; i < (FPB * D4) / 256; ++i) {
        const int g = i * 256 + tid;
        const int fl = g / D4;          // frame within tile (0..7), const-divide -> magic mul
        const int vv = g - fl * D4;     // float4 column (0..95)
        const int idx = s_idx[fl];
        float4 val;
        if (idx >= 0) {
            val = x4[idx * D4 + vv];
        } else {
            val = make_float4(0.f, 0.f, 0.f, 0.f);
        }
        o4[g] = val;                    // contiguous across the whole tile
    }
}

extern "C" void kernel_launch(void* const* d_in, const int* in_sizes, int n_in,
                              void* d_out, int out_size, void* d_ws, size_t ws_size,
                              hipStream_t stream) {
    const float* x = (const float*)d_in[0];
    const int* duration = (const int*)d_in[1];
    // d_in[2] = max_len (known constant 2048)

    float* out = (float*)d_out;                       // [B, MAXLEN, D] fp32
    float* mel_out = out + (size_t)BB * MAXLEN * DD;  // [B] mel_len, as float values
    int* csum = (int*)d_ws;                           // [B, T] workspace

    scan_kernel<<<BB, TT, 0, stream>>>(duration, csum, mel_out);
    expand_kernel<<<BB * TILES, 256, 0, stream>>>(x, csum, out);
}